// Round 3
// baseline (933.083 us; speedup 1.0000x reference)
//
#include <hip/hip_runtime.h>
#include <hip/hip_bf16.h>
#include <stdint.h>

#define H 256
#define W 512
#define NCG 18                     // 144/8 channel groups
#define AW 520                     // padded cols: x in [-2, 517]
#define AH 258                     // padded rows: y in [-2, 255]
#define XB 16                      // bytes per pixel per ci-group (8 bf16)
#define ROWB (AW*XB)               // 8320 B
#define CGB (AH*ROWB)              // 2,146,560 B per ci-group plane
#define ACTB ((size_t)NCG*(size_t)CGB)   // 38,638,080 B per activation buffer
#define KG 240                     // kgroups of 8 (13*18=234 real + 6 zero pad)
#define NCHUNK 30                  // K chunks of 64
#define CHUNKB 18432               // 8 kgroups * 144 co * 16 B
#define CHUNKFB 8192               // 8 kgroups * 64 co * 16 B (final layer)
#define WPH_B ((size_t)KG*144*16)  // 552,960 B per hidden layer packed W
#define WPF_B ((size_t)KG*64*16)   // 245,760 B final layer packed W (co padded to 64)

typedef float f32x4 __attribute__((ext_vector_type(4)));
typedef short bf16x8 __attribute__((ext_vector_type(8)));

__device__ __forceinline__ float bf2f(unsigned short u) {
  union { unsigned int i; float f; } v; v.i = ((unsigned int)u) << 16; return v.f;
}
__device__ __forceinline__ unsigned short f2bf(float f) {
  __hip_bfloat16 h = __float2bfloat16(f);
  return __builtin_bit_cast(unsigned short, h);
}
__device__ __forceinline__ void gload_lds16(const void* g, void* l) {
  __builtin_amdgcn_global_load_lds(
      (const __attribute__((address_space(1))) unsigned int*)g,
      (__attribute__((address_space(3))) unsigned int*)l, 16, 0, 0);
}

// ---------------- weight packing ----------------
// K-order is ci-group-major: kgrp = (ci/8)*13 + tap (taps of a plane adjacent
// in K -> activation kx-revisits hit L1/L2). kgrp 234..239 zero pad.
__global__ void k_pack_h(const float* __restrict__ wr, char* __restrict__ wph) {
  int idx = blockIdx.x * 256 + threadIdx.x;
  if (idx >= 10 * 144 * 144) return;
  int ci = idx % 144; int rem = idx / 144; int co = rem % 144; int layer = rem / 144;
  const float* src = wr + (size_t)((layer * 144 + co) * 144 + ci) * 25;
  unsigned short* dstL = (unsigned short*)(wph + (size_t)layer * WPH_B);
  int cig = ci >> 3, cis = ci & 7;
#pragma unroll
  for (int tap = 0; tap < 13; ++tap) {
    int ky = (tap >= 5) + (tap >= 10);
    int kx = tap - ky * 5;
    dstL[((size_t)(cig * 13 + tap) * 144 + co) * 8 + cis] = f2bf(src[ky * 5 + kx]);
  }
}
__global__ void k_pack_f(const float* __restrict__ wf, char* __restrict__ wpf) {
  int idx = blockIdx.x * 256 + threadIdx.x;
  if (idx >= 49 * 144) return;
  int ci = idx % 144; int co = idx / 144;
  const float* src = wf + (size_t)(co * 144 + ci) * 25;
  unsigned short* dst = (unsigned short*)wpf;
  int cig = ci >> 3, cis = ci & 7;
#pragma unroll
  for (int tap = 0; tap < 13; ++tap) {
    int ky = (tap >= 5) + (tap >= 10);
    int kx = tap - ky * 5;
    dst[((size_t)(cig * 13 + tap) * 64 + co) * 8 + cis] = f2bf(src[ky * 5 + kx]);
  }
}
__global__ void k_biaspad(const float* __restrict__ bf, float* __restrict__ bfp) {
  int i = threadIdx.x;
  bfp[i] = (i < 49) ? bf[i] : -1e30f;
}

// zero only the activation pad cells actually read: rows 0-1 (full) and
// cols {0,1,514,515} of rows 2..257, for both buffers, all 18 planes.
__global__ void k_zeropad(char* __restrict__ actA, char* __restrict__ actB) {
  int i = blockIdx.x * 256 + threadIdx.x;
  if (i >= 2 * 18 * 2064) return;
  int s = i % 2064; int p = i / 2064; int cig = p % 18; int buf = p / 18;
  char* base = (buf ? actB : actA) + (size_t)cig * CGB;
  int row, colpx;
  if (s < 1040) { row = s / 520; colpx = s - row * 520; }
  else { int s2 = s - 1040; row = 2 + (s2 >> 2); int m = s2 & 3; colpx = (m < 2) ? m : (512 + m); }
  uint4 z; z.x = z.y = z.z = z.w = 0u;
  *(uint4*)(base + (size_t)row * ROWB + (size_t)colpx * 16) = z;
}

// ---------------- first layer: 1 -> 144, strictly causal (12 taps) ----------------
__global__ void k_layer0(const float* __restrict__ x, const float* __restrict__ w0,
                         const float* __restrict__ b0, char* __restrict__ act) {
  int i = blockIdx.x * 256 + threadIdx.x;   // one thread per pixel
  int y = i >> 9, xx = i & 511;
  float xv[12];
#pragma unroll
  for (int tp = 0; tp < 12; ++tp) {
    int ky = (tp >= 5) + (tp >= 10);
    int kx = tp - ky * 5;
    int yy = y + ky - 2, xs = xx + kx - 2;
    bool ok = (yy >= 0) && (xs >= 0) && (xs < W);
    xv[tp] = ok ? x[yy * W + xs] : 0.f;
  }
  char* ob = act + (size_t)(y + 2) * ROWB + (size_t)(xx + 2) * XB;
  for (int cg = 0; cg < NCG; ++cg) {
    unsigned int us[4];
#pragma unroll
    for (int h2 = 0; h2 < 4; ++h2) {
      unsigned int lohi = 0;
#pragma unroll
      for (int p = 0; p < 2; ++p) {
        int co = cg * 8 + h2 * 2 + p;
        float a = b0[co];
#pragma unroll
        for (int tp = 0; tp < 12; ++tp) {
          int ky = (tp >= 5) + (tp >= 10);
          int kx = tp - ky * 5;
          a += w0[co * 25 + ky * 5 + kx] * xv[tp];
        }
        a = fmaxf(a, 0.f);
        lohi |= ((unsigned int)f2bf(a)) << (16 * p);
      }
      us[h2] = lohi;
    }
    uint4 v; v.x = us[0]; v.y = us[1]; v.z = us[2]; v.w = us[3];
    *(uint4*)(ob + (size_t)cg * CGB) = v;
  }
}

// ---------------- hidden conv: 144 -> 144, 13 taps, MFMA ----------------
// K=64 chunks (30 phases, ~700cy MFMA each), 2-wave blocks (4 independent
// barrier groups/CU), pair-unrolled B double-buffer (no reg copies), LDS
// weight double-buffer via global_load_lds with counted vmcnt(8) so the 8
// B-prefetch loads stay in flight across the barrier.
__global__ __launch_bounds__(128, 2)
void k_conv(const char* __restrict__ in, char* __restrict__ out,
            const char* __restrict__ wp, const float* __restrict__ bias, int res) {
  __shared__ __align__(16) char lA[2][CHUNKB];
  const int tid = threadIdx.x;
  const int wid = tid >> 6, lane = tid & 63;
  const int col = lane & 15, g = lane >> 4;

  int bid = blockIdx.x;                 // 1024 blocks
  int xcd = bid & 7, idx = bid >> 3;
  int by = xcd * 16 + (idx >> 3), bx = idx & 7;   // XCD gets contiguous 32-row band
  int y = by * 2 + wid, x0 = bx * 64;

  int pxo[4];
#pragma unroll
  for (int t = 0; t < 4; ++t) pxo[t] = (x0 + 16 * t + col) * XB;
  const char* bbase = in + (size_t)y * ROWB;

  f32x4 acc[9][4];
#pragma unroll
  for (int m = 0; m < 9; ++m)
#pragma unroll
    for (int t = 0; t < 4; ++t) acc[m][t] = (f32x4){0.f, 0.f, 0.f, 0.f};

  bf16x8 bA[8], bB[8];

  auto bload = [&](bf16x8 (&dst)[8], int c) __attribute__((always_inline)) {
#pragma unroll
    for (int s = 0; s < 2; ++s) {
      int kg = 8 * c + 4 * s + g;
      if (kg >= 234) kg = 0;            // pad kgroups: weights zero, any valid addr
      int cig = kg / 13;
      int tap = kg - cig * 13;
      int ky = (tap >= 5) + (tap >= 10);
      int kx = tap - ky * 5;
      int off = cig * (int)CGB + ky * (int)ROWB + (kx << 4);
#pragma unroll
      for (int t = 0; t < 4; ++t)
        dst[s * 4 + t] = *(const bf16x8*)(bbase + (size_t)(off + pxo[t]));
    }
  };

  auto stage = [&](char* ldsn, int c) __attribute__((always_inline)) {
    const char* wsrc = wp + (size_t)c * CHUNKB;
#pragma unroll
    for (int j0 = 0; j0 < 9; ++j0) {
      int j = wid + j0 * 2;
      gload_lds16(wsrc + (size_t)j * 1024 + (lane << 4), ldsn + j * 1024);
    }
  };

  auto domfma = [&](const char* ldsc, bf16x8 (&b)[8]) __attribute__((always_inline)) {
#pragma unroll
    for (int s = 0; s < 2; ++s) {
      const char* abase = ldsc + (((4 * s + g) * 144 + col) << 4);
#pragma unroll
      for (int m = 0; m < 9; ++m) {
        bf16x8 a = *(const bf16x8*)(abase + m * 256);
#pragma unroll
        for (int t = 0; t < 4; ++t)
          acc[m][t] = __builtin_amdgcn_mfma_f32_16x16x32_bf16(a, b[s * 4 + t], acc[m][t], 0, 0, 0);
      }
    }
  };

  auto phase = [&](const char* ldsc, char* ldsn, bf16x8 (&bcur)[8], bf16x8 (&bnext)[8],
                   int c) __attribute__((always_inline)) {
    stage(ldsn, c + 1);
    asm volatile("" ::: "memory");      // stage issues precede B prefetch (vmcnt order)
    bload(bnext, c + 1);
    asm volatile("" ::: "memory");
    domfma(ldsc, bcur);
    asm volatile("s_waitcnt vmcnt(8)" ::: "memory");  // stage done; 8 B loads in flight
    __builtin_amdgcn_s_barrier();
    asm volatile("" ::: "memory");
  };

  // prologue: chunk 0
  stage(&lA[0][0], 0);
  asm volatile("" ::: "memory");
  bload(bA, 0);
  asm volatile("s_waitcnt vmcnt(8)" ::: "memory");
  __builtin_amdgcn_s_barrier();
  asm volatile("" ::: "memory");

#pragma unroll 1
  for (int c = 0; c < NCHUNK - 2; c += 2) {
    phase(&lA[0][0], &lA[1][0], bA, bB, c);
    phase(&lA[1][0], &lA[0][0], bB, bA, c + 1);
  }
  phase(&lA[0][0], &lA[1][0], bA, bB, NCHUNK - 2);  // chunk 28, stages+loads 29
  domfma(&lA[1][0], bB);                            // chunk 29

  // epilogue: +bias, relu, optional residual (in-place on out), store bf16
  const int sub = (g & 1) * 8;
#pragma unroll
  for (int m = 0; m < 9; ++m) {
    int co0 = m * 16 + (g << 2);
    f32x4 bv = *(const f32x4*)(bias + co0);
    char* ob = out + (size_t)(co0 >> 3) * CGB + (size_t)(y + 2) * ROWB + sub + 32;
#pragma unroll
    for (int t = 0; t < 4; ++t) {
      char* oa = ob + pxo[t];
      float v0 = fmaxf(acc[m][t][0] + bv[0], 0.f);
      float v1 = fmaxf(acc[m][t][1] + bv[1], 0.f);
      float v2 = fmaxf(acc[m][t][2] + bv[2], 0.f);
      float v3 = fmaxf(acc[m][t][3] + bv[3], 0.f);
      if (res) {
        uint2 old = *(const uint2*)oa;
        v0 += bf2f((unsigned short)(old.x & 0xffff));
        v1 += bf2f((unsigned short)(old.x >> 16));
        v2 += bf2f((unsigned short)(old.y & 0xffff));
        v3 += bf2f((unsigned short)(old.y >> 16));
      }
      uint2 st;
      st.x = (unsigned int)f2bf(v0) | ((unsigned int)f2bf(v1) << 16);
      st.y = (unsigned int)f2bf(v2) | ((unsigned int)f2bf(v3) << 16);
      *(uint2*)oa = st;
    }
  }
}

// ---------------- final conv (144 -> 49 padded 64) + softmax ----------------
__global__ __launch_bounds__(128, 2)
void k_convf(const char* __restrict__ in, float* __restrict__ probs,
             const char* __restrict__ wp, const float* __restrict__ bfp) {
  __shared__ __align__(16) char lA[2][CHUNKFB];
  const int tid = threadIdx.x;
  const int wid = tid >> 6, lane = tid & 63;
  const int col = lane & 15, g = lane >> 4;

  int bid = blockIdx.x;
  int xcd = bid & 7, idx = bid >> 3;
  int by = xcd * 16 + (idx >> 3), bx = idx & 7;
  int y = by * 2 + wid, x0 = bx * 64;

  int pxo[4];
#pragma unroll
  for (int t = 0; t < 4; ++t) pxo[t] = (x0 + 16 * t + col) * XB;
  const char* bbase = in + (size_t)y * ROWB;

  f32x4 acc[4][4];
#pragma unroll
  for (int m = 0; m < 4; ++m)
#pragma unroll
    for (int t = 0; t < 4; ++t) acc[m][t] = (f32x4){0.f, 0.f, 0.f, 0.f};

  bf16x8 bA[8], bB[8];

  auto bload = [&](bf16x8 (&dst)[8], int c) __attribute__((always_inline)) {
#pragma unroll
    for (int s = 0; s < 2; ++s) {
      int kg = 8 * c + 4 * s + g;
      if (kg >= 234) kg = 0;
      int cig = kg / 13;
      int tap = kg - cig * 13;
      int ky = (tap >= 5) + (tap >= 10);
      int kx = tap - ky * 5;
      int off = cig * (int)CGB + ky * (int)ROWB + (kx << 4);
#pragma unroll
      for (int t = 0; t < 4; ++t)
        dst[s * 4 + t] = *(const bf16x8*)(bbase + (size_t)(off + pxo[t]));
    }
  };

  auto stage = [&](char* ldsn, int c) __attribute__((always_inline)) {
    const char* wsrc = wp + (size_t)c * CHUNKFB;
#pragma unroll
    for (int j0 = 0; j0 < 4; ++j0) {
      int j = wid + j0 * 2;
      gload_lds16(wsrc + (size_t)j * 1024 + (lane << 4), ldsn + j * 1024);
    }
  };

  auto domfma = [&](const char* ldsc, bf16x8 (&b)[8]) __attribute__((always_inline)) {
#pragma unroll
    for (int s = 0; s < 2; ++s) {
      const char* abase = ldsc + (((4 * s + g) * 64 + col) << 4);
#pragma unroll
      for (int m = 0; m < 4; ++m) {
        bf16x8 a = *(const bf16x8*)(abase + m * 256);
#pragma unroll
        for (int t = 0; t < 4; ++t)
          acc[m][t] = __builtin_amdgcn_mfma_f32_16x16x32_bf16(a, b[s * 4 + t], acc[m][t], 0, 0, 0);
      }
    }
  };

  auto phase = [&](const char* ldsc, char* ldsn, bf16x8 (&bcur)[8], bf16x8 (&bnext)[8],
                   int c) __attribute__((always_inline)) {
    stage(ldsn, c + 1);
    asm volatile("" ::: "memory");
    bload(bnext, c + 1);
    asm volatile("" ::: "memory");
    domfma(ldsc, bcur);
    asm volatile("s_waitcnt vmcnt(8)" ::: "memory");
    __builtin_amdgcn_s_barrier();
    asm volatile("" ::: "memory");
  };

  stage(&lA[0][0], 0);
  asm volatile("" ::: "memory");
  bload(bA, 0);
  asm volatile("s_waitcnt vmcnt(8)" ::: "memory");
  __builtin_amdgcn_s_barrier();
  asm volatile("" ::: "memory");

#pragma unroll 1
  for (int c = 0; c < NCHUNK - 2; c += 2) {
    phase(&lA[0][0], &lA[1][0], bA, bB, c);
    phase(&lA[1][0], &lA[0][0], bB, bA, c + 1);
  }
  phase(&lA[0][0], &lA[1][0], bA, bB, NCHUNK - 2);
  domfma(&lA[1][0], bB);

  // softmax over 49 channels per pixel; lanes (col, g0..3) hold the channel spread
#pragma unroll
  for (int t = 0; t < 4; ++t) {
    float lg[4][4];
    float mx = -1e30f;
#pragma unroll
    for (int m = 0; m < 4; ++m) {
      f32x4 bv = *(const f32x4*)(bfp + m * 16 + (g << 2));
#pragma unroll
      for (int r = 0; r < 4; ++r) {
        lg[m][r] = acc[m][t][r] + bv[r];
        mx = fmaxf(mx, lg[m][r]);
      }
    }
    mx = fmaxf(mx, __shfl_xor(mx, 16));
    mx = fmaxf(mx, __shfl_xor(mx, 32));
    float s = 0.f;
#pragma unroll
    for (int m = 0; m < 4; ++m)
#pragma unroll
      for (int r = 0; r < 4; ++r) {
        lg[m][r] = __expf(lg[m][r] - mx);
        s += lg[m][r];
      }
    s += __shfl_xor(s, 16);
    s += __shfl_xor(s, 32);
    float inv = 1.f / s;
    int xp = x0 + 16 * t + col;
    float* op = probs + (size_t)y * W + xp;
#pragma unroll
    for (int m = 0; m < 4; ++m)
#pragma unroll
      for (int r = 0; r < 4; ++r) {
        int co = m * 16 + (g << 2) + r;
        if (co < 49) op[(size_t)co * (H * W)] = lg[m][r] * inv;
      }
  }
}

// ---------------- importance mask + depth-to-space ----------------
__global__ void k_tmask(const float* __restrict__ x, float* __restrict__ out1) {
  int i = blockIdx.x * 256 + threadIdx.x;   // over 512*1024 outputs per g
  int yy = i >> 10, xx = i & 1023;
  float xv = x[(yy >> 1) * W + (xx >> 1)];
  float tc = floorf((xv + 1.0f) / (float)(2.0 / 47.0) + 1e-5f);
#pragma unroll 4
  for (int g = 0; g < 48; ++g)
    out1[(size_t)g * (512 * 1024) + i] = ((float)g < tc) ? 1.0f : 0.0f;
}

extern "C" void kernel_launch(void* const* d_in, const int* in_sizes, int n_in,
                              void* d_out, int out_size, void* d_ws, size_t ws_size,
                              hipStream_t stream) {
  const float* x  = (const float*)d_in[0];
  const float* w0 = (const float*)d_in[1];
  const float* b0 = (const float*)d_in[2];
  const float* wr = (const float*)d_in[3];
  const float* br = (const float*)d_in[4];
  const float* wf = (const float*)d_in[5];
  const float* bf = (const float*)d_in[6];

  char* ws   = (char*)d_ws;
  char* actA = ws;
  char* actB = ws + ACTB;
  char* wph  = ws + 2 * ACTB;
  char* wpf  = wph + 10 * WPH_B;
  float* bfp = (float*)(wpf + WPF_B);

  // zero weight pad regions (kgrp 234..239, final co 49..63) + bfp tail
  hipMemsetAsync(wph, 0, 10 * WPH_B + WPF_B + 256, stream);
  // zero only the activation pad cells that are read
  k_zeropad<<<(2 * 18 * 2064 + 255) / 256, 256, 0, stream>>>(actA, actB);

  k_pack_h<<<(10 * 144 * 144 + 255) / 256, 256, 0, stream>>>(wr, wph);
  k_pack_f<<<(49 * 144 + 255) / 256, 256, 0, stream>>>(wf, wpf);
  k_biaspad<<<1, 64, 0, stream>>>(bf, bfp);

  k_layer0<<<512, 256, 0, stream>>>(x, w0, b0, actA);

  for (int i = 0; i < 5; ++i) {
    k_conv<<<1024, 128, 0, stream>>>(actA, actB, wph + (size_t)(2 * i) * WPH_B,
                                     br + (2 * i) * 144, 0);
    k_conv<<<1024, 128, 0, stream>>>(actB, actA, wph + (size_t)(2 * i + 1) * WPH_B,
                                     br + (2 * i + 1) * 144, 1);
  }

  float* probs = (float*)d_out;
  k_convf<<<1024, 128, 0, stream>>>(actA, probs, wpf, bfp);
  k_tmask<<<2048, 256, 0, stream>>>(x, probs + (size_t)49 * H * W);
}

// Round 4
// 734.239 us; speedup vs baseline: 1.2708x; 1.2708x over previous
//
#include <hip/hip_runtime.h>
#include <hip/hip_bf16.h>
#include <stdint.h>

#define H 256
#define W 512
#define NCG 18                     // 144/8 channel groups
#define AW 520                     // padded cols: x in [-2, 517]
#define AH 258                     // padded rows: y in [-2, 255]
#define XB 16                      // bytes per pixel per ci-group (8 bf16)
#define ROWB (AW*XB)               // 8320 B
#define CGB (AH*ROWB)              // 2,146,560 B per ci-group plane
#define ACTB ((size_t)NCG*(size_t)CGB)   // 38,638,080 B per activation buffer
#define KG 236                     // kgroups of 8 (13*18=234 real + 2 zero pad)
#define NCHUNK 59                  // K chunks of 32
#define CHUNKB 9216                // 4 kgroups * 144 co * 16 B
#define CHUNKFB 4096               // 4 kgroups * 64 co * 16 B (final layer)
#define WPH_B ((size_t)KG*144*16)  // 543,744 B per hidden layer packed W
#define WPF_B ((size_t)KG*64*16)   // 241,664 B final layer packed W (co padded to 64)

typedef float f32x4 __attribute__((ext_vector_type(4)));
typedef short bf16x8 __attribute__((ext_vector_type(8)));

__device__ __forceinline__ float bf2f(unsigned short u) {
  union { unsigned int i; float f; } v; v.i = ((unsigned int)u) << 16; return v.f;
}
__device__ __forceinline__ unsigned short f2bf(float f) {
  __hip_bfloat16 h = __float2bfloat16(f);
  return __builtin_bit_cast(unsigned short, h);
}
__device__ __forceinline__ void gload_lds16(const void* g, void* l) {
  __builtin_amdgcn_global_load_lds(
      (const __attribute__((address_space(1))) unsigned int*)g,
      (__attribute__((address_space(3))) unsigned int*)l, 16, 0, 0);
}

// ---------------- weight packing ----------------
// K-order is ci-group-major: kgrp = (ci/8)*13 + tap, so all 13 taps of a
// ci-plane are adjacent in K -> activation kx-revisits hit L1/L2.
__global__ void k_pack_h(const float* __restrict__ wr, char* __restrict__ wph) {
  int idx = blockIdx.x * 256 + threadIdx.x;
  if (idx >= 10 * 144 * 144) return;
  int ci = idx % 144; int rem = idx / 144; int co = rem % 144; int layer = rem / 144;
  const float* src = wr + (size_t)((layer * 144 + co) * 144 + ci) * 25;
  unsigned short* dstL = (unsigned short*)(wph + (size_t)layer * WPH_B);
  int cig = ci >> 3, cis = ci & 7;
#pragma unroll
  for (int tap = 0; tap < 13; ++tap) {
    int ky = (tap >= 5) + (tap >= 10);
    int kx = tap - ky * 5;
    dstL[((size_t)(cig * 13 + tap) * 144 + co) * 8 + cis] = f2bf(src[ky * 5 + kx]);
  }
}
__global__ void k_pack_f(const float* __restrict__ wf, char* __restrict__ wpf) {
  int idx = blockIdx.x * 256 + threadIdx.x;
  if (idx >= 49 * 144) return;
  int ci = idx % 144; int co = idx / 144;
  const float* src = wf + (size_t)(co * 144 + ci) * 25;
  unsigned short* dst = (unsigned short*)wpf;
  int cig = ci >> 3, cis = ci & 7;
#pragma unroll
  for (int tap = 0; tap < 13; ++tap) {
    int ky = (tap >= 5) + (tap >= 10);
    int kx = tap - ky * 5;
    dst[((size_t)(cig * 13 + tap) * 64 + co) * 8 + cis] = f2bf(src[ky * 5 + kx]);
  }
}
__global__ void k_biaspad(const float* __restrict__ bf, float* __restrict__ bfp) {
  int i = threadIdx.x;
  bfp[i] = (i < 49) ? bf[i] : -1e30f;
}

// zero only the activation pad cells actually read: rows 0-1 (full) and
// cols {0,1,514,515} of rows 2..257, for both buffers, all 18 planes.
__global__ void k_zeropad(char* __restrict__ actA, char* __restrict__ actB) {
  int i = blockIdx.x * 256 + threadIdx.x;
  if (i >= 2 * 18 * 2064) return;
  int s = i % 2064; int p = i / 2064; int cig = p % 18; int buf = p / 18;
  char* base = (buf ? actB : actA) + (size_t)cig * CGB;
  int row, colpx;
  if (s < 1040) { row = s / 520; colpx = s - row * 520; }
  else { int s2 = s - 1040; row = 2 + (s2 >> 2); int m = s2 & 3; colpx = (m < 2) ? m : (512 + m); }
  uint4 z; z.x = z.y = z.z = z.w = 0u;
  *(uint4*)(base + (size_t)row * ROWB + (size_t)colpx * 16) = z;
}

// ---------------- first layer: 1 -> 144, strictly causal (12 taps) ----------------
__global__ void k_layer0(const float* __restrict__ x, const float* __restrict__ w0,
                         const float* __restrict__ b0, char* __restrict__ act) {
  int i = blockIdx.x * 256 + threadIdx.x;   // one thread per pixel
  int y = i >> 9, xx = i & 511;
  float xv[12];
#pragma unroll
  for (int tp = 0; tp < 12; ++tp) {
    int ky = (tp >= 5) + (tp >= 10);
    int kx = tp - ky * 5;
    int yy = y + ky - 2, xs = xx + kx - 2;
    bool ok = (yy >= 0) && (xs >= 0) && (xs < W);
    xv[tp] = ok ? x[yy * W + xs] : 0.f;
  }
  char* ob = act + (size_t)(y + 2) * ROWB + (size_t)(xx + 2) * XB;
  for (int cg = 0; cg < NCG; ++cg) {
    unsigned int us[4];
#pragma unroll
    for (int h2 = 0; h2 < 4; ++h2) {
      unsigned int lohi = 0;
#pragma unroll
      for (int p = 0; p < 2; ++p) {
        int co = cg * 8 + h2 * 2 + p;
        float a = b0[co];
#pragma unroll
        for (int tp = 0; tp < 12; ++tp) {
          int ky = (tp >= 5) + (tp >= 10);
          int kx = tp - ky * 5;
          a += w0[co * 25 + ky * 5 + kx] * xv[tp];
        }
        a = fmaxf(a, 0.f);
        lohi |= ((unsigned int)f2bf(a)) << (16 * p);
      }
      us[h2] = lohi;
    }
    uint4 v; v.x = us[0]; v.y = us[1]; v.z = us[2]; v.w = us[3];
    *(uint4*)(ob + (size_t)cg * CGB) = v;
  }
}

// ---------------- hidden conv: 144 -> 144, 13 taps, MFMA ----------------
// Round-2 structure (K=32 chunks, 4-wave blocks, grid 512) + DEPTH-2 pipeline:
// triple-buffered LDS weights and triple-rotated B register sets give stage
// and B prefetch two full phases (~2800cy) to cover HBM miss latency.
// Counted vmcnt(10) retires only stage(c+1); newer prefetch stays in flight.
__global__ __launch_bounds__(256, 2)
void k_conv(const char* __restrict__ in, char* __restrict__ out,
            const char* __restrict__ wp, const float* __restrict__ bias, int res) {
  __shared__ __align__(16) char lA[3][CHUNKB];
  const int tid = threadIdx.x;
  const int wid = tid >> 6, lane = tid & 63;
  const int col = lane & 15, g = lane >> 4;

  int bid = blockIdx.x;                 // 512 blocks
  int xcd = bid & 7, idx = bid >> 3;
  int by = xcd * 8 + (idx >> 3), bx = idx & 7;   // XCD gets contiguous 32-row band
  int y = by * 4 + wid, x0 = bx * 64;

  int pxo[4];
#pragma unroll
  for (int t = 0; t < 4; ++t) pxo[t] = (x0 + 16 * t + col) * XB;
  const char* bbase = in + (size_t)y * ROWB;

  f32x4 acc[9][4];
#pragma unroll
  for (int m = 0; m < 9; ++m)
#pragma unroll
    for (int t = 0; t < 4; ++t) acc[m][t] = (f32x4){0.f, 0.f, 0.f, 0.f};

  bf16x8 bA[4], bB[4], bC[4];

  auto bload = [&](bf16x8 (&dst)[4], int c) __attribute__((always_inline)) {
    int kg = 4 * c + g;
    if (kg >= 234) kg = 0;              // pad kgroups: weights zero, any valid addr
    int cig = kg / 13;
    int tap = kg - cig * 13;
    int ky = (tap >= 5) + (tap >= 10);
    int kx = tap - ky * 5;
    int off = cig * (int)CGB + ky * (int)ROWB + (kx << 4);
#pragma unroll
    for (int t = 0; t < 4; ++t) dst[t] = *(const bf16x8*)(bbase + (size_t)(off + pxo[t]));
  };

  auto stage = [&](char* ldsn, int c) __attribute__((always_inline)) {
    const char* wsrc = wp + (size_t)c * CHUNKB;
#pragma unroll
    for (int j0 = 0; j0 < 3; ++j0) {
      int j = wid + j0 * 4;
      if (j < 9) gload_lds16(wsrc + (size_t)j * 1024 + (lane << 4), ldsn + j * 1024);
    }
  };

  auto domfma = [&](const char* ldsc, bf16x8 (&bcur)[4]) __attribute__((always_inline)) {
    const char* abase = ldsc + ((g * 144 + col) << 4);
    __builtin_amdgcn_s_setprio(1);
#pragma unroll
    for (int m = 0; m < 9; ++m) {
      bf16x8 a = *(const bf16x8*)(abase + m * 256);
#pragma unroll
      for (int t = 0; t < 4; ++t)
        acc[m][t] = __builtin_amdgcn_mfma_f32_16x16x32_bf16(a, bcur[t], acc[m][t], 0, 0, 0);
    }
    __builtin_amdgcn_s_setprio(0);
  };

  // phase c: stage chunk c+2 into ldsW, B-load chunk c+2 into bLoad,
  // compute chunk c from ldsR with bUse.
  auto phase = [&](const char* ldsR, char* ldsW, bf16x8 (&bUse)[4], bf16x8 (&bLoad)[4],
                   int c) __attribute__((always_inline)) {
    stage(ldsW, c + 2);
    asm volatile("" ::: "memory");      // stage issues precede B prefetch (vmcnt order)
    bload(bLoad, c + 2);
    asm volatile("" ::: "memory");
    domfma(ldsR, bUse);
    asm volatile("s_waitcnt vmcnt(10)" ::: "memory");  // stage(c+1) done; rest in flight
    __builtin_amdgcn_s_barrier();
    asm volatile("" ::: "memory");
  };

  // prologue: chunks 0 and 1
  stage(&lA[0][0], 0);
  stage(&lA[1][0], 1);
  asm volatile("" ::: "memory");
  bload(bA, 0);
  bload(bB, 1);
  asm volatile("s_waitcnt vmcnt(10)" ::: "memory");    // stage(0) done
  __builtin_amdgcn_s_barrier();
  asm volatile("" ::: "memory");

#pragma unroll 1
  for (int c = 0; c < NCHUNK - 2; c += 3) {            // 57 = 3*19
    phase(&lA[0][0], &lA[2][0], bA, bC, c);
    phase(&lA[1][0], &lA[0][0], bB, bA, c + 1);
    phase(&lA[2][0], &lA[1][0], bC, bB, c + 2);
  }
  // tail: chunk 57 (lds[0], bA) then 58 (lds[1], bB); stage(58)/bload(58)
  // were issued in phase 56.
  domfma(&lA[0][0], bA);
  asm volatile("s_waitcnt vmcnt(4)" ::: "memory");     // stage(58) done
  __builtin_amdgcn_s_barrier();
  asm volatile("" ::: "memory");
  domfma(&lA[1][0], bB);

  // epilogue: +bias, relu, optional residual (in-place on out), store bf16
  const int sub = (g & 1) * 8;
#pragma unroll
  for (int m = 0; m < 9; ++m) {
    int co0 = m * 16 + (g << 2);
    f32x4 bv = *(const f32x4*)(bias + co0);
    char* ob = out + (size_t)(co0 >> 3) * CGB + (size_t)(y + 2) * ROWB + sub + 32;
#pragma unroll
    for (int t = 0; t < 4; ++t) {
      char* oa = ob + pxo[t];
      float v0 = fmaxf(acc[m][t][0] + bv[0], 0.f);
      float v1 = fmaxf(acc[m][t][1] + bv[1], 0.f);
      float v2 = fmaxf(acc[m][t][2] + bv[2], 0.f);
      float v3 = fmaxf(acc[m][t][3] + bv[3], 0.f);
      if (res) {
        uint2 old = *(const uint2*)oa;
        v0 += bf2f((unsigned short)(old.x & 0xffff));
        v1 += bf2f((unsigned short)(old.x >> 16));
        v2 += bf2f((unsigned short)(old.y & 0xffff));
        v3 += bf2f((unsigned short)(old.y >> 16));
      }
      uint2 st;
      st.x = (unsigned int)f2bf(v0) | ((unsigned int)f2bf(v1) << 16);
      st.y = (unsigned int)f2bf(v2) | ((unsigned int)f2bf(v3) << 16);
      *(uint2*)oa = st;
    }
  }
}

// ---------------- final conv (144 -> 49 padded 64) + softmax ----------------
__global__ __launch_bounds__(256, 2)
void k_convf(const char* __restrict__ in, float* __restrict__ probs,
             const char* __restrict__ wp, const float* __restrict__ bfp) {
  __shared__ __align__(16) char lA[3][CHUNKFB];
  const int tid = threadIdx.x;
  const int wid = tid >> 6, lane = tid & 63;
  const int col = lane & 15, g = lane >> 4;

  int bid = blockIdx.x;
  int xcd = bid & 7, idx = bid >> 3;
  int by = xcd * 8 + (idx >> 3), bx = idx & 7;
  int y = by * 4 + wid, x0 = bx * 64;

  int pxo[4];
#pragma unroll
  for (int t = 0; t < 4; ++t) pxo[t] = (x0 + 16 * t + col) * XB;
  const char* bbase = in + (size_t)y * ROWB;

  f32x4 acc[4][4];
#pragma unroll
  for (int m = 0; m < 4; ++m)
#pragma unroll
    for (int t = 0; t < 4; ++t) acc[m][t] = (f32x4){0.f, 0.f, 0.f, 0.f};

  bf16x8 bA[4], bB[4], bC[4];

  auto bload = [&](bf16x8 (&dst)[4], int c) __attribute__((always_inline)) {
    int kg = 4 * c + g;
    if (kg >= 234) kg = 0;
    int cig = kg / 13;
    int tap = kg - cig * 13;
    int ky = (tap >= 5) + (tap >= 10);
    int kx = tap - ky * 5;
    int off = cig * (int)CGB + ky * (int)ROWB + (kx << 4);
#pragma unroll
    for (int t = 0; t < 4; ++t) dst[t] = *(const bf16x8*)(bbase + (size_t)(off + pxo[t]));
  };

  auto stage = [&](char* ldsn, int c) __attribute__((always_inline)) {
    const char* wsrc = wp + (size_t)c * CHUNKFB;
    if (wid < 4) gload_lds16(wsrc + (size_t)wid * 1024 + (lane << 4), ldsn + wid * 1024);
  };

  auto domfma = [&](const char* ldsc, bf16x8 (&bcur)[4]) __attribute__((always_inline)) {
    const char* abase = ldsc + ((g * 64 + col) << 4);
    __builtin_amdgcn_s_setprio(1);
#pragma unroll
    for (int m = 0; m < 4; ++m) {
      bf16x8 a = *(const bf16x8*)(abase + m * 256);
#pragma unroll
      for (int t = 0; t < 4; ++t)
        acc[m][t] = __builtin_amdgcn_mfma_f32_16x16x32_bf16(a, bcur[t], acc[m][t], 0, 0, 0);
    }
    __builtin_amdgcn_s_setprio(0);
  };

  auto phase = [&](const char* ldsR, char* ldsW, bf16x8 (&bUse)[4], bf16x8 (&bLoad)[4],
                   int c) __attribute__((always_inline)) {
    stage(ldsW, c + 2);
    asm volatile("" ::: "memory");
    bload(bLoad, c + 2);
    asm volatile("" ::: "memory");
    domfma(ldsR, bUse);
    asm volatile("s_waitcnt vmcnt(9)" ::: "memory");   // stage(c+1) done
    __builtin_amdgcn_s_barrier();
    asm volatile("" ::: "memory");
  };

  stage(&lA[0][0], 0);
  stage(&lA[1][0], 1);
  asm volatile("" ::: "memory");
  bload(bA, 0);
  bload(bB, 1);
  asm volatile("s_waitcnt vmcnt(9)" ::: "memory");
  __builtin_amdgcn_s_barrier();
  asm volatile("" ::: "memory");

#pragma unroll 1
  for (int c = 0; c < NCHUNK - 2; c += 3) {
    phase(&lA[0][0], &lA[2][0], bA, bC, c);
    phase(&lA[1][0], &lA[0][0], bB, bA, c + 1);
    phase(&lA[2][0], &lA[1][0], bC, bB, c + 2);
  }
  domfma(&lA[0][0], bA);
  asm volatile("s_waitcnt vmcnt(4)" ::: "memory");
  __builtin_amdgcn_s_barrier();
  asm volatile("" ::: "memory");
  domfma(&lA[1][0], bB);

  // softmax over 49 channels per pixel; lanes (col, g0..3) hold the channel spread
#pragma unroll
  for (int t = 0; t < 4; ++t) {
    float lg[4][4];
    float mx = -1e30f;
#pragma unroll
    for (int m = 0; m < 4; ++m) {
      f32x4 bv = *(const f32x4*)(bfp + m * 16 + (g << 2));
#pragma unroll
      for (int r = 0; r < 4; ++r) {
        lg[m][r] = acc[m][t][r] + bv[r];
        mx = fmaxf(mx, lg[m][r]);
      }
    }
    mx = fmaxf(mx, __shfl_xor(mx, 16));
    mx = fmaxf(mx, __shfl_xor(mx, 32));
    float s = 0.f;
#pragma unroll
    for (int m = 0; m < 4; ++m)
#pragma unroll
      for (int r = 0; r < 4; ++r) {
        lg[m][r] = __expf(lg[m][r] - mx);
        s += lg[m][r];
      }
    s += __shfl_xor(s, 16);
    s += __shfl_xor(s, 32);
    float inv = 1.f / s;
    int xp = x0 + 16 * t + col;
    float* op = probs + (size_t)y * W + xp;
#pragma unroll
    for (int m = 0; m < 4; ++m)
#pragma unroll
      for (int r = 0; r < 4; ++r) {
        int co = m * 16 + (g << 2) + r;
        if (co < 49) op[(size_t)co * (H * W)] = lg[m][r] * inv;
      }
  }
}

// ---------------- importance mask + depth-to-space ----------------
__global__ void k_tmask(const float* __restrict__ x, float* __restrict__ out1) {
  int i = blockIdx.x * 256 + threadIdx.x;   // over 512*1024 outputs per g
  int yy = i >> 10, xx = i & 1023;
  float xv = x[(yy >> 1) * W + (xx >> 1)];
  float tc = floorf((xv + 1.0f) / (float)(2.0 / 47.0) + 1e-5f);
#pragma unroll 4
  for (int g = 0; g < 48; ++g)
    out1[(size_t)g * (512 * 1024) + i] = ((float)g < tc) ? 1.0f : 0.0f;
}

extern "C" void kernel_launch(void* const* d_in, const int* in_sizes, int n_in,
                              void* d_out, int out_size, void* d_ws, size_t ws_size,
                              hipStream_t stream) {
  const float* x  = (const float*)d_in[0];
  const float* w0 = (const float*)d_in[1];
  const float* b0 = (const float*)d_in[2];
  const float* wr = (const float*)d_in[3];
  const float* br = (const float*)d_in[4];
  const float* wf = (const float*)d_in[5];
  const float* bf = (const float*)d_in[6];

  char* ws   = (char*)d_ws;
  char* actA = ws;
  char* actB = ws + ACTB;
  char* wph  = ws + 2 * ACTB;
  char* wpf  = wph + 10 * WPH_B;
  float* bfp = (float*)(wpf + WPF_B);

  // zero weight pad regions (kgrp 234/235, final co 49..63) + bfp tail
  hipMemsetAsync(wph, 0, 10 * WPH_B + WPF_B + 256, stream);
  // zero only the activation pad cells that are read
  k_zeropad<<<(2 * 18 * 2064 + 255) / 256, 256, 0, stream>>>(actA, actB);

  k_pack_h<<<(10 * 144 * 144 + 255) / 256, 256, 0, stream>>>(wr, wph);
  k_pack_f<<<(49 * 144 + 255) / 256, 256, 0, stream>>>(wf, wpf);
  k_biaspad<<<1, 64, 0, stream>>>(bf, bfp);

  k_layer0<<<512, 256, 0, stream>>>(x, w0, b0, actA);

  for (int i = 0; i < 5; ++i) {
    k_conv<<<512, 256, 0, stream>>>(actA, actB, wph + (size_t)(2 * i) * WPH_B,
                                    br + (2 * i) * 144, 0);
    k_conv<<<512, 256, 0, stream>>>(actB, actA, wph + (size_t)(2 * i + 1) * WPH_B,
                                    br + (2 * i + 1) * 144, 1);
  }

  float* probs = (float*)d_out;
  k_convf<<<512, 256, 0, stream>>>(actA, probs, wpf, bfp);
  k_tmask<<<2048, 256, 0, stream>>>(x, probs + (size_t)49 * H * W);
}